// Round 15
// baseline (256.868 us; speedup 1.0000x reference)
//
#include <hip/hip_runtime.h>

// Per-pixel attention over 32 "boxes" (fp32 in/out), MFMA f16 compute.
//   q,k,v: [32 box][4 batch][64 ch][6400 pix]
//   S[i,j] = <q[i,:,p],k[j,:,p]>/8 ; w = softmax_j ; out[i,c,p] = sum_j w[i,j] v[j,c,p]
//
// R15 vs R14: R14's counters: Occupancy 20%, VGPR 72 (compiler sank the T14 prefetch),
// MfmaUtil 1%, VALU 7% -> the block is a serial ~9-barrier HBM-latency chain with only
// 2 resident blocks/CU (LDS 64KB) to cover it. This round halves the block: PIX=8,
// NT=256 (4 waves, wave w <-> px {w,w+4}), LDS 32KB -> 5 blocks/CU (20 waves/CU),
// 2.5x the independent barrier chains; grid 3200. Dataflow/swizzles/T14 unchanged,
// only index widths. OB region is 16KB with swzO(L)=L^(((L>>9)&7)<<4) (bijective;
// frag-writes spread over 8 banks; readback conflict-balanced).
// Pre-committed risk: 8px rows = 32B global granules (64B line spans 2 tiles);
// XCD swizzle + L2 must absorb the other half -- FETCH >= 450MB means it didn't.

#define NBOX    32
#define NBATCH  4
#define CH      64
#define HW      6400
#define PIX     8
#define NT      256
#define NTILES  (HW / PIX)         // 800
#define NUNITS  (NBATCH * NTILES)  // 3200

typedef __fp16 f16;
typedef f16   f16x2  __attribute__((ext_vector_type(2)));
typedef f16   f16x8  __attribute__((ext_vector_type(8)));
typedef float f32x16 __attribute__((ext_vector_type(16)));

#define SYNC() do { __builtin_amdgcn_sched_barrier(0); __syncthreads(); \
                    __builtin_amdgcn_sched_barrier(0); } while (0)

__device__ __forceinline__ int swz(int L) {
    return L ^ ((((L >> 9) & 3) | (((L >> 13) & 1) << 2)) << 4);
}
__device__ __forceinline__ int swzO(int L) {     // OB: i*512 + cL*16 + px*2 (16KB)
    return L ^ (((L >> 9) & 7) << 4);
}

#define ZERO16 {0.f,0.f,0.f,0.f,0.f,0.f,0.f,0.f,0.f,0.f,0.f,0.f,0.f,0.f,0.f,0.f}

__global__ __launch_bounds__(NT, 2)
void box_attn_mfma(const float* __restrict__ q, const float* __restrict__ k,
                   const float* __restrict__ v, float* __restrict__ out) {
    __shared__ char sm[32768];
    char* const KF = sm;            // phase1: K frags (c-half), 16KB
    char* const QF = sm + 16384;    // phase1: Q frags (c-half), 16KB
    char* const VF = sm;            // phase2: V frags (ct-slice), 16KB
    char* const OB = sm + 16384;    // phase2: O staging f16, 16KB

    const int t    = threadIdx.x;
    const int lane = t & 63;
    const int w    = t >> 6;        // wave 0..3 -> pixels {w, w+4}
    const int h    = lane >> 5;
    const int bid  = blockIdx.x;
    const int unit = (bid & 7) * (NUNITS / 8) + (bid >> 3);   // XCD swizzle (3200%8==0)
    const int b    = unit / NTILES;
    const int p0   = (unit % NTILES) * PIX;

    // ---- T14 split staging ----
    auto load_kq = [&](const float* __restrict__ src, int chalf, float4* r) {
#pragma unroll
        for (int rep = 0; rep < 2; ++rep) {
            int u = rep * NT + t;                       // 0..511
            int pxq = u & 1, qq = (u >> 1) & 3, kcL = (u >> 3) & 1, box = (u >> 4) & 31;
            int cb = chalf + kcL * 16 + qq * 4;
            const float* g = src + ((size_t)((box * NBATCH + b) * CH + cb)) * HW + p0 + pxq * 4;
            r[rep * 4 + 0] = *(const float4*)(g);
            r[rep * 4 + 1] = *(const float4*)(g + HW);
            r[rep * 4 + 2] = *(const float4*)(g + 2 * HW);
            r[rep * 4 + 3] = *(const float4*)(g + 3 * HW);
        }
    };
    auto write_kq = [&](char* dst, const float4* r) {
#pragma unroll
        for (int rep = 0; rep < 2; ++rep) {
            int u = rep * NT + t;
            int pxq = u & 1, qq = (u >> 1) & 3, kcL = (u >> 3) & 1, box = (u >> 4) & 31;
            int Lb = kcL * 1024 + (box + 32 * (qq & 1)) * 16 + (qq >> 1) * 8;
            const float* f0 = &r[rep * 4 + 0].x;
            const float* f1 = &r[rep * 4 + 1].x;
            const float* f2 = &r[rep * 4 + 2].x;
            const float* f3 = &r[rep * 4 + 3].x;
#pragma unroll
            for (int pi = 0; pi < 4; ++pi) {
                union { f16x2 hh[2]; uint2 u2; } val;
                val.hh[0] = __builtin_amdgcn_cvt_pkrtz(f0[pi], f1[pi]);
                val.hh[1] = __builtin_amdgcn_cvt_pkrtz(f2[pi], f3[pi]);
                *(uint2*)(dst + swz((pxq * 4 + pi) * 2048 + Lb)) = val.u2;
            }
        }
    };
    auto load_v = [&](int coff, float4* r) {   // coff = ct*32
        const size_t JS = (size_t)NBATCH * CH * HW;
#pragma unroll
        for (int rep = 0; rep < 2; ++rep) {
            int u = rep * NT + t;
            int pxq = u & 1, qq = (u >> 1) & 3, jc = (u >> 3) & 1, cL = (u >> 4) & 31;
            const float* g = v + ((size_t)(((jc * 16 + qq * 4) * NBATCH + b) * CH + coff + cL)) * HW
                               + p0 + pxq * 4;
            r[rep * 4 + 0] = *(const float4*)(g);
            r[rep * 4 + 1] = *(const float4*)(g + JS);
            r[rep * 4 + 2] = *(const float4*)(g + 2 * JS);
            r[rep * 4 + 3] = *(const float4*)(g + 3 * JS);
        }
    };
    auto write_v = [&](const float4* r) {
#pragma unroll
        for (int rep = 0; rep < 2; ++rep) {
            int u = rep * NT + t;
            int pxq = u & 1, qq = (u >> 1) & 3, jc = (u >> 3) & 1, cL = (u >> 4) & 31;
            int Lb = jc * 1024 + (cL + 32 * (qq & 1)) * 16 + (qq >> 1) * 8;
            const float* f0 = &r[rep * 4 + 0].x;
            const float* f1 = &r[rep * 4 + 1].x;
            const float* f2 = &r[rep * 4 + 2].x;
            const float* f3 = &r[rep * 4 + 3].x;
#pragma unroll
            for (int pi = 0; pi < 4; ++pi) {
                union { f16x2 hh[2]; uint2 u2; } val;
                val.hh[0] = __builtin_amdgcn_cvt_pkrtz(f0[pi], f1[pi]);
                val.hh[1] = __builtin_amdgcn_cvt_pkrtz(f2[pi], f3[pi]);
                *(uint2*)(VF + swz((pxq * 4 + pi) * 2048 + Lb)) = val.u2;
            }
        }
    };

    auto smax_pack = [&](const f32x16& s, f16x8& fr0, f16x8& fr1) {
        float p[16];
        float m = s[0];
#pragma unroll
        for (int r = 1; r < 16; ++r) m = fmaxf(m, s[r]);
        m = fmaxf(m, __shfl_xor(m, 32, 64));
        float sum = 0.f;
#pragma unroll
        for (int r = 0; r < 16; ++r) { p[r] = __expf((s[r] - m) * 0.125f); sum += p[r]; }
        sum += __shfl_xor(sum, 32, 64);
        float inv = 1.f / sum;
        union { f16x8 v8; f16x2 hh[4]; } u0, u1;
#pragma unroll
        for (int kk = 0; kk < 4; ++kk) {
            u0.hh[kk] = __builtin_amdgcn_cvt_pkrtz(p[2 * kk] * inv,     p[2 * kk + 1] * inv);
            u1.hh[kk] = __builtin_amdgcn_cvt_pkrtz(p[8 + 2 * kk] * inv, p[9 + 2 * kk] * inv);
        }
        fr0 = u0.v8; fr1 = u1.v8;
    };

    // ================= Phase 1: S^T = K . Q^T =================
    f32x16 sA = ZERO16, sB = ZERO16;
    float4 kr[8], qr[8], vr[8];

    load_kq(k, 0, kr);  load_kq(q, 0, qr);
    write_kq(KF, kr);   write_kq(QF, qr);
    load_kq(k, 32, kr); load_kq(q, 32, qr);  // T14: K1/Q1 in flight across MFMA half0
    SYNC();
#pragma unroll
    for (int kcL = 0; kcL < 2; ++kcL) {
        int LA = kcL * 1024 + lane * 16;
        f16x8 a0 = *(const f16x8*)(KF + swz(w * 2048 + LA));
        f16x8 b0 = *(const f16x8*)(QF + swz(w * 2048 + LA));
        sA = __builtin_amdgcn_mfma_f32_32x32x16_f16(a0, b0, sA, 0, 0, 0);
        f16x8 a1 = *(const f16x8*)(KF + swz((w + 4) * 2048 + LA));
        f16x8 b1 = *(const f16x8*)(QF + swz((w + 4) * 2048 + LA));
        sB = __builtin_amdgcn_mfma_f32_32x32x16_f16(a1, b1, sB, 0, 0, 0);
    }
    SYNC();
    write_kq(KF, kr); write_kq(QF, qr);
    load_v(0, vr);                           // T14: V0 in flight across MFMA half1
    SYNC();
#pragma unroll
    for (int kcL = 0; kcL < 2; ++kcL) {
        int LA = kcL * 1024 + lane * 16;
        f16x8 a0 = *(const f16x8*)(KF + swz(w * 2048 + LA));
        f16x8 b0 = *(const f16x8*)(QF + swz(w * 2048 + LA));
        sA = __builtin_amdgcn_mfma_f32_32x32x16_f16(a0, b0, sA, 0, 0, 0);
        f16x8 a1 = *(const f16x8*)(KF + swz((w + 4) * 2048 + LA));
        f16x8 b1 = *(const f16x8*)(QF + swz((w + 4) * 2048 + LA));
        sB = __builtin_amdgcn_mfma_f32_32x32x16_f16(a1, b1, sB, 0, 0, 0);
    }
    SYNC();   // all Kf/Qf reads done -> VF region reusable

    write_v(vr);                             // V0 -> VF
    load_v(32, vr);                          // T14: V1 in flight across softmax + PV ct0
    f16x8 pA0, pA1, pB0, pB1;
    smax_pack(sA, pA0, pA1);
    smax_pack(sB, pB0, pB1);
    SYNC();                                  // V0 staged

    // ================= Phase 2: O^T = V^T . P^T =================
    // ---- ct = 0 ----
    {
        f32x16 oA = ZERO16, oB = ZERO16;
        {
            int LA = lane * 16;
            f16x8 av0 = *(const f16x8*)(VF + swz(w * 2048 + LA));
            oA = __builtin_amdgcn_mfma_f32_32x32x16_f16(av0, pA0, oA, 0, 0, 0);
            f16x8 av1 = *(const f16x8*)(VF + swz((w + 4) * 2048 + LA));
            oB = __builtin_amdgcn_mfma_f32_32x32x16_f16(av1, pB0, oB, 0, 0, 0);
        }
        {
            int LA = 1024 + lane * 16;
            f16x8 av0 = *(const f16x8*)(VF + swz(w * 2048 + LA));
            oA = __builtin_amdgcn_mfma_f32_32x32x16_f16(av0, pA1, oA, 0, 0, 0);
            f16x8 av1 = *(const f16x8*)(VF + swz((w + 4) * 2048 + LA));
            oB = __builtin_amdgcn_mfma_f32_32x32x16_f16(av1, pB1, oB, 0, 0, 0);
        }
        const int i = lane & 31;
#pragma unroll
        for (int r = 0; r < 16; ++r) {
            int cL = (r & 3) + 8 * (r >> 2) + 4 * h;
            *(f16*)(OB + swzO(i * 512 + cL * 16 + w * 2))       = (f16)oA[r];
            *(f16*)(OB + swzO(i * 512 + cL * 16 + (w + 4) * 2)) = (f16)oB[r];
        }
        SYNC();   // OB complete; VF readers done

        write_v(vr);   // V1 -> VF (landed under softmax+PV)

#pragma unroll
        for (int rep = 0; rep < 4; ++rep) {
            int row = rep * NT + t;   // 1024 rows = 32 i x 32 cL
            int oi = row >> 5, cL = row & 31;
            union { uint4 u4; f16x2 hh[4]; } ra;
            ra.u4 = *(const uint4*)(OB + swzO(oi * 512 + cL * 16));
            float* op = out + ((size_t)((oi * NBATCH + b) * CH + cL)) * HW + p0;
            float4 s0 = { (float)ra.hh[0][0], (float)ra.hh[0][1], (float)ra.hh[1][0], (float)ra.hh[1][1] };
            float4 s1 = { (float)ra.hh[2][0], (float)ra.hh[2][1], (float)ra.hh[3][0], (float)ra.hh[3][1] };
            *(float4*)(op + 0) = s0;
            *(float4*)(op + 4) = s1;
        }
        SYNC();   // V1 staged; OB readers done before ct1 frag-writes
    }
    // ---- ct = 1 ----
    {
        f32x16 oA = ZERO16, oB = ZERO16;
        {
            int LA = lane * 16;
            f16x8 av0 = *(const f16x8*)(VF + swz(w * 2048 + LA));
            oA = __builtin_amdgcn_mfma_f32_32x32x16_f16(av0, pA0, oA, 0, 0, 0);
            f16x8 av1 = *(const f16x8*)(VF + swz((w + 4) * 2048 + LA));
            oB = __builtin_amdgcn_mfma_f32_32x32x16_f16(av1, pB0, oB, 0, 0, 0);
        }
        {
            int LA = 1024 + lane * 16;
            f16x8 av0 = *(const f16x8*)(VF + swz(w * 2048 + LA));
            oA = __builtin_amdgcn_mfma_f32_32x32x16_f16(av0, pA1, oA, 0, 0, 0);
            f16x8 av1 = *(const f16x8*)(VF + swz((w + 4) * 2048 + LA));
            oB = __builtin_amdgcn_mfma_f32_32x32x16_f16(av1, pB1, oB, 0, 0, 0);
        }
        const int i = lane & 31;
#pragma unroll
        for (int r = 0; r < 16; ++r) {
            int cL = (r & 3) + 8 * (r >> 2) + 4 * h;
            *(f16*)(OB + swzO(i * 512 + cL * 16 + w * 2))       = (f16)oA[r];
            *(f16*)(OB + swzO(i * 512 + cL * 16 + (w + 4) * 2)) = (f16)oB[r];
        }
        SYNC();   // OB complete

#pragma unroll
        for (int rep = 0; rep < 4; ++rep) {
            int row = rep * NT + t;
            int oi = row >> 5, cL = row & 31;
            union { uint4 u4; f16x2 hh[4]; } ra;
            ra.u4 = *(const uint4*)(OB + swzO(oi * 512 + cL * 16));
            float* op = out + ((size_t)((oi * NBATCH + b) * CH + 32 + cL)) * HW + p0;
            float4 s0 = { (float)ra.hh[0][0], (float)ra.hh[0][1], (float)ra.hh[1][0], (float)ra.hh[1][1] };
            float4 s1 = { (float)ra.hh[2][0], (float)ra.hh[2][1], (float)ra.hh[3][0], (float)ra.hh[3][1] };
            *(float4*)(op + 0) = s0;
            *(float4*)(op + 4) = s1;
        }
    }
}

extern "C" void kernel_launch(void* const* d_in, const int* in_sizes, int n_in,
                              void* d_out, int out_size, void* d_ws, size_t ws_size,
                              hipStream_t stream) {
    const float* q = (const float*)d_in[0];
    const float* k = (const float*)d_in[1];
    const float* v = (const float*)d_in[2];
    float* o = (float*)d_out;
    dim3 grid(NUNITS);   // 3200 blocks of 256
    box_attn_mfma<<<grid, NT, 0, stream>>>(q, k, v, o);
}

// Round 16
// 234.060 us; speedup vs baseline: 1.0974x; 1.0974x over previous
//
#include <hip/hip_runtime.h>

// Per-pixel attention over 32 "boxes" (fp32 in/out), MFMA f16 compute.
//   q,k,v: [32 box][4 batch][64 ch][6400 pix]
//   S[i,j] = <q[i,:,p],k[j,:,p]>/8 ; w = softmax_j ; out[i,c,p] = sum_j w[i,j] v[j,c,p]
//
// R16 vs R14/R15: R15 (5 blocks/CU, 8px) regressed -- granularity tax, occupancy is not
// the lever. All designs sit at ~2.05 TB/s active BW because the HBM request queue is
// only ever ~1 stage deep per block and collapses at each barrier. R16 issues ALL SIX
// load stages (K0,Q0,K1,Q1,V0,V1 = 384KB/block) at t=0 into six register arrays
// (192 VGPR in flight); vmcnt in-order semantics let the K0/Q0 LDS writes wait only on
// the oldest loads. launch_bounds(512,1) -> VGPR cap 256 (empirical law 256/arg2),
// 1 block/CU, 8 waves. Every barrier wait becomes pure bandwidth time.
// Dataflow/swizzles/fenced-SYNC identical to R14 (verified absmax 0.0156), PIX=16.
// Spill tripwire: WRITE >> 205MB -> drop to 4 held arrays next round.

#define NBOX    32
#define NBATCH  4
#define CH      64
#define HW      6400
#define PIX     16
#define NT      512
#define NTILES  (HW / PIX)         // 400
#define NUNITS  (NBATCH * NTILES)  // 1600

typedef __fp16 f16;
typedef f16   f16x2  __attribute__((ext_vector_type(2)));
typedef f16   f16x8  __attribute__((ext_vector_type(8)));
typedef float f32x16 __attribute__((ext_vector_type(16)));

#define SYNC() do { __builtin_amdgcn_sched_barrier(0); __syncthreads(); \
                    __builtin_amdgcn_sched_barrier(0); } while (0)

__device__ __forceinline__ int swz(int L) {
    return L ^ ((((L >> 9) & 3) | (((L >> 13) & 1) << 2)) << 4);
}
__device__ __forceinline__ int swzO(int L) {
    return L ^ ((((L >> 10) & 7) ^ ((L >> 5) & 7)) << 4);
}

#define ZERO16 {0.f,0.f,0.f,0.f,0.f,0.f,0.f,0.f,0.f,0.f,0.f,0.f,0.f,0.f,0.f,0.f}

__global__ __launch_bounds__(NT, 1)
void box_attn_mfma(const float* __restrict__ q, const float* __restrict__ k,
                   const float* __restrict__ v, float* __restrict__ out) {
    __shared__ char sm[65536];
    char* const KF = sm;            // phase1: K frags (c-half), 32KB
    char* const QF = sm + 32768;    // phase1: Q frags (c-half), 32KB
    char* const VF = sm;            // phase2: V frags (ct-slice), 32KB
    char* const OB = sm + 32768;    // phase2: O staging f16, 32KB

    const int t    = threadIdx.x;
    const int lane = t & 63;
    const int w    = t >> 6;        // wave 0..7 -> pixels {w, w+8}
    const int h    = lane >> 5;
    const int bid  = blockIdx.x;
    const int unit = (bid & 7) * (NUNITS / 8) + (bid >> 3);   // XCD swizzle
    const int b    = unit / NTILES;
    const int p0   = (unit % NTILES) * PIX;

    auto load_kq = [&](const float* __restrict__ src, int chalf, float4* r) {
#pragma unroll
        for (int rep = 0; rep < 2; ++rep) {
            int u = rep * NT + t;
            int pxq = u & 3, qq = (u >> 2) & 3, kcL = (u >> 4) & 1, box = (u >> 5) & 31;
            int cb = chalf + kcL * 16 + qq * 4;
            const float* g = src + ((size_t)((box * NBATCH + b) * CH + cb)) * HW + p0 + pxq * 4;
            r[rep * 4 + 0] = *(const float4*)(g);
            r[rep * 4 + 1] = *(const float4*)(g + HW);
            r[rep * 4 + 2] = *(const float4*)(g + 2 * HW);
            r[rep * 4 + 3] = *(const float4*)(g + 3 * HW);
        }
    };
    auto write_kq = [&](char* dst, const float4* r) {
#pragma unroll
        for (int rep = 0; rep < 2; ++rep) {
            int u = rep * NT + t;
            int pxq = u & 3, qq = (u >> 2) & 3, kcL = (u >> 4) & 1, box = (u >> 5) & 31;
            int Lb = kcL * 1024 + (box + 32 * (qq & 1)) * 16 + (qq >> 1) * 8;
            const float* f0 = &r[rep * 4 + 0].x;
            const float* f1 = &r[rep * 4 + 1].x;
            const float* f2 = &r[rep * 4 + 2].x;
            const float* f3 = &r[rep * 4 + 3].x;
#pragma unroll
            for (int pi = 0; pi < 4; ++pi) {
                union { f16x2 hh[2]; uint2 u2; } val;
                val.hh[0] = __builtin_amdgcn_cvt_pkrtz(f0[pi], f1[pi]);
                val.hh[1] = __builtin_amdgcn_cvt_pkrtz(f2[pi], f3[pi]);
                *(uint2*)(dst + swz((pxq * 4 + pi) * 2048 + Lb)) = val.u2;
            }
        }
    };
    auto load_v = [&](int coff, float4* r) {   // coff = ct*32
        const size_t JS = (size_t)NBATCH * CH * HW;
#pragma unroll
        for (int rep = 0; rep < 2; ++rep) {
            int u = rep * NT + t;
            int pxq = u & 3, qq = (u >> 2) & 3, jc = (u >> 4) & 1, cL = (u >> 5) & 31;
            const float* g = v + ((size_t)(((jc * 16 + qq * 4) * NBATCH + b) * CH + coff + cL)) * HW
                               + p0 + pxq * 4;
            r[rep * 4 + 0] = *(const float4*)(g);
            r[rep * 4 + 1] = *(const float4*)(g + JS);
            r[rep * 4 + 2] = *(const float4*)(g + 2 * JS);
            r[rep * 4 + 3] = *(const float4*)(g + 3 * JS);
        }
    };
    auto write_v = [&](const float4* r) {
#pragma unroll
        for (int rep = 0; rep < 2; ++rep) {
            int u = rep * NT + t;
            int pxq = u & 3, qq = (u >> 2) & 3, jc = (u >> 4) & 1, cL = (u >> 5) & 31;
            int Lb = jc * 1024 + (cL + 32 * (qq & 1)) * 16 + (qq >> 1) * 8;
            const float* f0 = &r[rep * 4 + 0].x;
            const float* f1 = &r[rep * 4 + 1].x;
            const float* f2 = &r[rep * 4 + 2].x;
            const float* f3 = &r[rep * 4 + 3].x;
#pragma unroll
            for (int pi = 0; pi < 4; ++pi) {
                union { f16x2 hh[2]; uint2 u2; } val;
                val.hh[0] = __builtin_amdgcn_cvt_pkrtz(f0[pi], f1[pi]);
                val.hh[1] = __builtin_amdgcn_cvt_pkrtz(f2[pi], f3[pi]);
                *(uint2*)(VF + swz((pxq * 4 + pi) * 2048 + Lb)) = val.u2;
            }
        }
    };

    auto smax_pack = [&](const f32x16& s, f16x8& fr0, f16x8& fr1) {
        float p[16];
        float m = s[0];
#pragma unroll
        for (int r = 1; r < 16; ++r) m = fmaxf(m, s[r]);
        m = fmaxf(m, __shfl_xor(m, 32, 64));
        float sum = 0.f;
#pragma unroll
        for (int r = 0; r < 16; ++r) { p[r] = __expf((s[r] - m) * 0.125f); sum += p[r]; }
        sum += __shfl_xor(sum, 32, 64);
        float inv = 1.f / sum;
        union { f16x8 v8; f16x2 hh[4]; } u0, u1;
#pragma unroll
        for (int kk = 0; kk < 4; ++kk) {
            u0.hh[kk] = __builtin_amdgcn_cvt_pkrtz(p[2 * kk] * inv,     p[2 * kk + 1] * inv);
            u1.hh[kk] = __builtin_amdgcn_cvt_pkrtz(p[8 + 2 * kk] * inv, p[9 + 2 * kk] * inv);
        }
        fr0 = u0.v8; fr1 = u1.v8;
    };

    // ========= issue the ENTIRE block input stream (384KB) before anything else ========
    f32x16 sA = ZERO16, sB = ZERO16;
    float4 kr[8], qr[8], kr2[8], qr2[8], vr0[8], vr1[8];

    load_kq(k, 0, kr);   load_kq(q, 0, qr);     // oldest in queue
    load_kq(k, 32, kr2); load_kq(q, 32, qr2);
    load_v(0, vr0);      load_v(32, vr1);       // newest in queue

    write_kq(KF, kr);    write_kq(QF, qr);      // vmcnt waits only the oldest 32 instrs
    SYNC();

    // ================= Phase 1: S^T = K . Q^T =================
#pragma unroll
    for (int kcL = 0; kcL < 2; ++kcL) {
        int LA = kcL * 1024 + lane * 16;
        f16x8 a0 = *(const f16x8*)(KF + swz(w * 2048 + LA));
        f16x8 b0 = *(const f16x8*)(QF + swz(w * 2048 + LA));
        sA = __builtin_amdgcn_mfma_f32_32x32x16_f16(a0, b0, sA, 0, 0, 0);
        f16x8 a1 = *(const f16x8*)(KF + swz((w + 8) * 2048 + LA));
        f16x8 b1 = *(const f16x8*)(QF + swz((w + 8) * 2048 + LA));
        sB = __builtin_amdgcn_mfma_f32_32x32x16_f16(a1, b1, sB, 0, 0, 0);
    }
    SYNC();
    write_kq(KF, kr2); write_kq(QF, qr2);       // landed long ago
    SYNC();
#pragma unroll
    for (int kcL = 0; kcL < 2; ++kcL) {
        int LA = kcL * 1024 + lane * 16;
        f16x8 a0 = *(const f16x8*)(KF + swz(w * 2048 + LA));
        f16x8 b0 = *(const f16x8*)(QF + swz(w * 2048 + LA));
        sA = __builtin_amdgcn_mfma_f32_32x32x16_f16(a0, b0, sA, 0, 0, 0);
        f16x8 a1 = *(const f16x8*)(KF + swz((w + 8) * 2048 + LA));
        f16x8 b1 = *(const f16x8*)(QF + swz((w + 8) * 2048 + LA));
        sB = __builtin_amdgcn_mfma_f32_32x32x16_f16(a1, b1, sB, 0, 0, 0);
    }
    SYNC();   // all Kf/Qf reads done -> VF region reusable

    write_v(vr0);                               // V0 -> VF
    f16x8 pA0, pA1, pB0, pB1;
    smax_pack(sA, pA0, pA1);
    smax_pack(sB, pB0, pB1);
    SYNC();                                     // V0 staged

    // ================= Phase 2: O^T = V^T . P^T =================
    // ---- ct = 0 ----
    {
        f32x16 oA = ZERO16, oB = ZERO16;
        {
            int LA = lane * 16;
            f16x8 av0 = *(const f16x8*)(VF + swz(w * 2048 + LA));
            oA = __builtin_amdgcn_mfma_f32_32x32x16_f16(av0, pA0, oA, 0, 0, 0);
            f16x8 av1 = *(const f16x8*)(VF + swz((w + 8) * 2048 + LA));
            oB = __builtin_amdgcn_mfma_f32_32x32x16_f16(av1, pB0, oB, 0, 0, 0);
        }
        {
            int LA = 1024 + lane * 16;
            f16x8 av0 = *(const f16x8*)(VF + swz(w * 2048 + LA));
            oA = __builtin_amdgcn_mfma_f32_32x32x16_f16(av0, pA1, oA, 0, 0, 0);
            f16x8 av1 = *(const f16x8*)(VF + swz((w + 8) * 2048 + LA));
            oB = __builtin_amdgcn_mfma_f32_32x32x16_f16(av1, pB1, oB, 0, 0, 0);
        }
        const int i = lane & 31;
#pragma unroll
        for (int r = 0; r < 16; ++r) {
            int cL = (r & 3) + 8 * (r >> 2) + 4 * h;
            *(f16*)(OB + swzO(i * 1024 + cL * 32 + w * 2))       = (f16)oA[r];
            *(f16*)(OB + swzO(i * 1024 + cL * 32 + (w + 8) * 2)) = (f16)oB[r];
        }
        SYNC();   // OB complete; VF readers done

        write_v(vr1);   // V1 -> VF (landed long ago)

#pragma unroll
        for (int rep = 0; rep < 2; ++rep) {
            int row = rep * NT + t;
            int oi = row >> 5, cL = row & 31;
            union { uint4 u4; f16x2 hh[4]; } ra, rb;
            ra.u4 = *(const uint4*)(OB + swzO(oi * 1024 + cL * 32));
            rb.u4 = *(const uint4*)(OB + swzO(oi * 1024 + cL * 32 + 16));
            float* op = out + ((size_t)((oi * NBATCH + b) * CH + cL)) * HW + p0;
            float4 s0 = { (float)ra.hh[0][0], (float)ra.hh[0][1], (float)ra.hh[1][0], (float)ra.hh[1][1] };
            float4 s1 = { (float)ra.hh[2][0], (float)ra.hh[2][1], (float)ra.hh[3][0], (float)ra.hh[3][1] };
            float4 s2 = { (float)rb.hh[0][0], (float)rb.hh[0][1], (float)rb.hh[1][0], (float)rb.hh[1][1] };
            float4 s3 = { (float)rb.hh[2][0], (float)rb.hh[2][1], (float)rb.hh[3][0], (float)rb.hh[3][1] };
            *(float4*)(op + 0)  = s0;
            *(float4*)(op + 4)  = s1;
            *(float4*)(op + 8)  = s2;
            *(float4*)(op + 12) = s3;
        }
        SYNC();   // V1 staged; OB readers done before ct1 frag-writes
    }
    // ---- ct = 1 ----
    {
        f32x16 oA = ZERO16, oB = ZERO16;
        {
            int LA = lane * 16;
            f16x8 av0 = *(const f16x8*)(VF + swz(w * 2048 + LA));
            oA = __builtin_amdgcn_mfma_f32_32x32x16_f16(av0, pA0, oA, 0, 0, 0);
            f16x8 av1 = *(const f16x8*)(VF + swz((w + 8) * 2048 + LA));
            oB = __builtin_amdgcn_mfma_f32_32x32x16_f16(av1, pB0, oB, 0, 0, 0);
        }
        {
            int LA = 1024 + lane * 16;
            f16x8 av0 = *(const f16x8*)(VF + swz(w * 2048 + LA));
            oA = __builtin_amdgcn_mfma_f32_32x32x16_f16(av0, pA1, oA, 0, 0, 0);
            f16x8 av1 = *(const f16x8*)(VF + swz((w + 8) * 2048 + LA));
            oB = __builtin_amdgcn_mfma_f32_32x32x16_f16(av1, pB1, oB, 0, 0, 0);
        }
        const int i = lane & 31;
#pragma unroll
        for (int r = 0; r < 16; ++r) {
            int cL = (r & 3) + 8 * (r >> 2) + 4 * h;
            *(f16*)(OB + swzO(i * 1024 + cL * 32 + w * 2))       = (f16)oA[r];
            *(f16*)(OB + swzO(i * 1024 + cL * 32 + (w + 8) * 2)) = (f16)oB[r];
        }
        SYNC();   // OB complete

#pragma unroll
        for (int rep = 0; rep < 2; ++rep) {
            int row = rep * NT + t;
            int oi = row >> 5, cL = row & 31;
            union { uint4 u4; f16x2 hh[4]; } ra, rb;
            ra.u4 = *(const uint4*)(OB + swzO(oi * 1024 + cL * 32));
            rb.u4 = *(const uint4*)(OB + swzO(oi * 1024 + cL * 32 + 16));
            float* op = out + ((size_t)((oi * NBATCH + b) * CH + 32 + cL)) * HW + p0;
            float4 s0 = { (float)ra.hh[0][0], (float)ra.hh[0][1], (float)ra.hh[1][0], (float)ra.hh[1][1] };
            float4 s1 = { (float)ra.hh[2][0], (float)ra.hh[2][1], (float)ra.hh[3][0], (float)ra.hh[3][1] };
            float4 s2 = { (float)rb.hh[0][0], (float)rb.hh[0][1], (float)rb.hh[1][0], (float)rb.hh[1][1] };
            float4 s3 = { (float)rb.hh[2][0], (float)rb.hh[2][1], (float)rb.hh[3][0], (float)rb.hh[3][1] };
            *(float4*)(op + 0)  = s0;
            *(float4*)(op + 4)  = s1;
            *(float4*)(op + 8)  = s2;
            *(float4*)(op + 12) = s3;
        }
    }
}

extern "C" void kernel_launch(void* const* d_in, const int* in_sizes, int n_in,
                              void* d_out, int out_size, void* d_ws, size_t ws_size,
                              hipStream_t stream) {
    const float* q = (const float*)d_in[0];
    const float* k = (const float*)d_in[1];
    const float* v = (const float*)d_in[2];
    float* o = (float*)d_out;
    dim3 grid(NUNITS);   // 1600 blocks of 512
    box_attn_mfma<<<grid, NT, 0, stream>>>(q, k, v, o);
}

// Round 17
// 222.048 us; speedup vs baseline: 1.1568x; 1.0541x over previous
//
#include <hip/hip_runtime.h>

// Per-pixel attention over 32 "boxes" (fp32 in/out), MFMA f16 compute.
//   q,k,v: [32 box][4 batch][64 ch][6400 pix]
//   S[i,j] = <q[i,:,p],k[j,:,p]>/8 ; w = softmax_j ; out[i,c,p] = sum_j w[i,j] v[j,c,p]
//
// R17 vs R16: __syncthreads emits s_waitcnt vmcnt(0) before s_barrier -> every one of
// the ~9 barriers drained the whole HBM queue (why all prefetch schemes stalled at
// ~2.3 TB/s active). This round ports the guide's T3/T4 pattern:
//   - SYNCR(): s_waitcnt lgkmcnt(0) + RAW s_barrier (no vmcnt drain). LDS consistency
//     needs only lgkm; load results live in registers, protected by counted vmcnt.
//   - Loads are asm volatile global_load_dwordx4 (unsinkable, exact issue order):
//     K0,Q0,K1,Q1 at t=0 (32/thread); V0 after K0/Q0-write; V1 after V0-write.
//   - Counted waits: vmcnt(16) -> K0/Q0 write; vmcnt(8) -> K1/Q1; vmcnt(0) -> V0/V1.
//   - sched_barrier(0) around every wait (rule 18); no compiler global loads exist in
//     the pipeline region, so the counts are exact UNLESS the allocator spills
//     (scratch ops count in vmcnt) -- tripwire: absmax garbage + VGPR=256.
// Frag math / swizzles / OB staging identical to R16 (verified absmax 0.0156).
// launch_bounds(512,1): cap 256; ~190 peak regs -> 1 block/CU, 8 waves, full-depth
// stream. 1600 blocks / 256 CUs = 6.25 rounds x ~22-28us predicted block time.

#define NBOX    32
#define NBATCH  4
#define CH      64
#define HW      6400
#define PIX     16
#define NT      512
#define NTILES  (HW / PIX)         // 400
#define NUNITS  (NBATCH * NTILES)  // 1600

typedef __fp16 f16;
typedef f16   f16x2  __attribute__((ext_vector_type(2)));
typedef f16   f16x8  __attribute__((ext_vector_type(8)));
typedef float f32x16 __attribute__((ext_vector_type(16)));

// raw barrier: LDS-drain only, vmcnt sails across
#define SYNCR() do { __builtin_amdgcn_sched_barrier(0); \
    asm volatile("s_waitcnt lgkmcnt(0)" ::: "memory"); \
    __builtin_amdgcn_s_barrier(); \
    __builtin_amdgcn_sched_barrier(0); } while (0)

#define VWAIT(N) do { __builtin_amdgcn_sched_barrier(0); \
    asm volatile("s_waitcnt vmcnt(" #N ")" ::: "memory"); \
    __builtin_amdgcn_sched_barrier(0); } while (0)

__device__ __forceinline__ float4 gload(const float* p) {
    float4 d;
    asm volatile("global_load_dwordx4 %0, %1, off" : "=v"(d) : "v"(p));
    return d;
}

__device__ __forceinline__ int swz(int L) {
    return L ^ ((((L >> 9) & 3) | (((L >> 13) & 1) << 2)) << 4);
}
__device__ __forceinline__ int swzO(int L) {
    return L ^ ((((L >> 10) & 7) ^ ((L >> 5) & 7)) << 4);
}

#define ZERO16 {0.f,0.f,0.f,0.f,0.f,0.f,0.f,0.f,0.f,0.f,0.f,0.f,0.f,0.f,0.f,0.f}

__global__ __launch_bounds__(NT, 1)
void box_attn_mfma(const float* __restrict__ q, const float* __restrict__ k,
                   const float* __restrict__ v, float* __restrict__ out) {
    __shared__ char sm[65536];
    char* const KF = sm;            // phase1: K frags (c-half), 32KB
    char* const QF = sm + 32768;    // phase1: Q frags (c-half), 32KB
    char* const VF = sm;            // phase2: V frags (ct-slice), 32KB
    char* const OB = sm + 32768;    // phase2: O staging f16, 32KB

    const int t    = threadIdx.x;
    const int lane = t & 63;
    const int w    = t >> 6;        // wave 0..7 -> pixels {w, w+8}
    const int h    = lane >> 5;
    const int bid  = blockIdx.x;
    const int unit = (bid & 7) * (NUNITS / 8) + (bid >> 3);   // XCD swizzle
    const int b    = unit / NTILES;
    const int p0   = (unit % NTILES) * PIX;

    // ---- pinned-issue loads (asm volatile; order = vmcnt count order) ----
    auto load_kq = [&](const float* __restrict__ src, int chalf, float4* r) {
#pragma unroll
        for (int rep = 0; rep < 2; ++rep) {
            int u = rep * NT + t;
            int pxq = u & 3, qq = (u >> 2) & 3, kcL = (u >> 4) & 1, box = (u >> 5) & 31;
            int cb = chalf + kcL * 16 + qq * 4;
            const float* g = src + ((size_t)((box * NBATCH + b) * CH + cb)) * HW + p0 + pxq * 4;
            r[rep * 4 + 0] = gload(g);
            r[rep * 4 + 1] = gload(g + HW);
            r[rep * 4 + 2] = gload(g + 2 * HW);
            r[rep * 4 + 3] = gload(g + 3 * HW);
        }
    };
    auto write_kq = [&](char* dst, const float4* r) {
#pragma unroll
        for (int rep = 0; rep < 2; ++rep) {
            int u = rep * NT + t;
            int pxq = u & 3, qq = (u >> 2) & 3, kcL = (u >> 4) & 1, box = (u >> 5) & 31;
            int Lb = kcL * 1024 + (box + 32 * (qq & 1)) * 16 + (qq >> 1) * 8;
            const float* f0 = &r[rep * 4 + 0].x;
            const float* f1 = &r[rep * 4 + 1].x;
            const float* f2 = &r[rep * 4 + 2].x;
            const float* f3 = &r[rep * 4 + 3].x;
#pragma unroll
            for (int pi = 0; pi < 4; ++pi) {
                union { f16x2 hh[2]; uint2 u2; } val;
                val.hh[0] = __builtin_amdgcn_cvt_pkrtz(f0[pi], f1[pi]);
                val.hh[1] = __builtin_amdgcn_cvt_pkrtz(f2[pi], f3[pi]);
                *(uint2*)(dst + swz((pxq * 4 + pi) * 2048 + Lb)) = val.u2;
            }
        }
    };
    auto load_v = [&](int coff, float4* r) {   // coff = ct*32
        const size_t JS = (size_t)NBATCH * CH * HW;
#pragma unroll
        for (int rep = 0; rep < 2; ++rep) {
            int u = rep * NT + t;
            int pxq = u & 3, qq = (u >> 2) & 3, jc = (u >> 4) & 1, cL = (u >> 5) & 31;
            const float* g = v + ((size_t)(((jc * 16 + qq * 4) * NBATCH + b) * CH + coff + cL)) * HW
                               + p0 + pxq * 4;
            r[rep * 4 + 0] = gload(g);
            r[rep * 4 + 1] = gload(g + JS);
            r[rep * 4 + 2] = gload(g + 2 * JS);
            r[rep * 4 + 3] = gload(g + 3 * JS);
        }
    };
    auto write_v = [&](const float4* r) {
#pragma unroll
        for (int rep = 0; rep < 2; ++rep) {
            int u = rep * NT + t;
            int pxq = u & 3, qq = (u >> 2) & 3, jc = (u >> 4) & 1, cL = (u >> 5) & 31;
            int Lb = jc * 1024 + (cL + 32 * (qq & 1)) * 16 + (qq >> 1) * 8;
            const float* f0 = &r[rep * 4 + 0].x;
            const float* f1 = &r[rep * 4 + 1].x;
            const float* f2 = &r[rep * 4 + 2].x;
            const float* f3 = &r[rep * 4 + 3].x;
#pragma unroll
            for (int pi = 0; pi < 4; ++pi) {
                union { f16x2 hh[2]; uint2 u2; } val;
                val.hh[0] = __builtin_amdgcn_cvt_pkrtz(f0[pi], f1[pi]);
                val.hh[1] = __builtin_amdgcn_cvt_pkrtz(f2[pi], f3[pi]);
                *(uint2*)(VF + swz((pxq * 4 + pi) * 2048 + Lb)) = val.u2;
            }
        }
    };

    auto smax_pack = [&](const f32x16& s, f16x8& fr0, f16x8& fr1) {
        float p[16];
        float m = s[0];
#pragma unroll
        for (int r = 1; r < 16; ++r) m = fmaxf(m, s[r]);
        m = fmaxf(m, __shfl_xor(m, 32, 64));
        float sum = 0.f;
#pragma unroll
        for (int r = 0; r < 16; ++r) { p[r] = __expf((s[r] - m) * 0.125f); sum += p[r]; }
        sum += __shfl_xor(sum, 32, 64);
        float inv = 1.f / sum;
        union { f16x8 v8; f16x2 hh[4]; } u0, u1;
#pragma unroll
        for (int kk = 0; kk < 4; ++kk) {
            u0.hh[kk] = __builtin_amdgcn_cvt_pkrtz(p[2 * kk] * inv,     p[2 * kk + 1] * inv);
            u1.hh[kk] = __builtin_amdgcn_cvt_pkrtz(p[8 + 2 * kk] * inv, p[9 + 2 * kk] * inv);
        }
        fr0 = u0.v8; fr1 = u1.v8;
    };

    // ====== issue K0,Q0,K1,Q1 (32 loads/thread) at t=0; counted-wait consumption ======
    float4 kr[8], qr[8], kr2[8], qr2[8], vr[8];
    load_kq(k, 0, kr);   load_kq(q, 0, qr);     // oldest 16
    load_kq(k, 32, kr2); load_kq(q, 32, qr2);   // next 16

    VWAIT(16);                                  // kr,qr landed (kr2,qr2 still in flight)
    write_kq(KF, kr);    write_kq(QF, qr);
    load_v(0, vr);                              // V0 in flight across phase-1 half0
    f32x16 sA = ZERO16, sB = ZERO16;
    SYNCR();

    // ================= Phase 1: S^T = K . Q^T =================
#pragma unroll
    for (int kcL = 0; kcL < 2; ++kcL) {
        int LA = kcL * 1024 + lane * 16;
        f16x8 a0 = *(const f16x8*)(KF + swz(w * 2048 + LA));
        f16x8 b0 = *(const f16x8*)(QF + swz(w * 2048 + LA));
        sA = __builtin_amdgcn_mfma_f32_32x32x16_f16(a0, b0, sA, 0, 0, 0);
        f16x8 a1 = *(const f16x8*)(KF + swz((w + 8) * 2048 + LA));
        f16x8 b1 = *(const f16x8*)(QF + swz((w + 8) * 2048 + LA));
        sB = __builtin_amdgcn_mfma_f32_32x32x16_f16(a1, b1, sB, 0, 0, 0);
    }
    SYNCR();
    VWAIT(8);                                   // kr2,qr2 landed (only V0 outstanding)
    write_kq(KF, kr2); write_kq(QF, qr2);
    SYNCR();
#pragma unroll
    for (int kcL = 0; kcL < 2; ++kcL) {
        int LA = kcL * 1024 + lane * 16;
        f16x8 a0 = *(const f16x8*)(KF + swz(w * 2048 + LA));
        f16x8 b0 = *(const f16x8*)(QF + swz(w * 2048 + LA));
        sA = __builtin_amdgcn_mfma_f32_32x32x16_f16(a0, b0, sA, 0, 0, 0);
        f16x8 a1 = *(const f16x8*)(KF + swz((w + 8) * 2048 + LA));
        f16x8 b1 = *(const f16x8*)(QF + swz((w + 8) * 2048 + LA));
        sB = __builtin_amdgcn_mfma_f32_32x32x16_f16(a1, b1, sB, 0, 0, 0);
    }
    SYNCR();   // all Kf/Qf reads done -> VF region reusable

    VWAIT(0);                                   // V0 landed
    write_v(vr);                                // V0 -> VF
    load_v(32, vr);                             // V1 in flight across softmax + PV ct0
    f16x8 pA0, pA1, pB0, pB1;
    smax_pack(sA, pA0, pA1);
    smax_pack(sB, pB0, pB1);
    SYNCR();                                    // V0 staged

    // ================= Phase 2: O^T = V^T . P^T =================
    // ---- ct = 0 ----
    {
        f32x16 oA = ZERO16, oB = ZERO16;
        {
            int LA = lane * 16;
            f16x8 av0 = *(const f16x8*)(VF + swz(w * 2048 + LA));
            oA = __builtin_amdgcn_mfma_f32_32x32x16_f16(av0, pA0, oA, 0, 0, 0);
            f16x8 av1 = *(const f16x8*)(VF + swz((w + 8) * 2048 + LA));
            oB = __builtin_amdgcn_mfma_f32_32x32x16_f16(av1, pB0, oB, 0, 0, 0);
        }
        {
            int LA = 1024 + lane * 16;
            f16x8 av0 = *(const f16x8*)(VF + swz(w * 2048 + LA));
            oA = __builtin_amdgcn_mfma_f32_32x32x16_f16(av0, pA1, oA, 0, 0, 0);
            f16x8 av1 = *(const f16x8*)(VF + swz((w + 8) * 2048 + LA));
            oB = __builtin_amdgcn_mfma_f32_32x32x16_f16(av1, pB1, oB, 0, 0, 0);
        }
        const int i = lane & 31;
#pragma unroll
        for (int r = 0; r < 16; ++r) {
            int cL = (r & 3) + 8 * (r >> 2) + 4 * h;
            *(f16*)(OB + swzO(i * 1024 + cL * 32 + w * 2))       = (f16)oA[r];
            *(f16*)(OB + swzO(i * 1024 + cL * 32 + (w + 8) * 2)) = (f16)oB[r];
        }
        SYNCR();   // OB complete; VF readers done

        VWAIT(0);                               // V1 landed
        write_v(vr);                            // V1 -> VF

#pragma unroll
        for (int rep = 0; rep < 2; ++rep) {
            int row = rep * NT + t;
            int oi = row >> 5, cL = row & 31;
            union { uint4 u4; f16x2 hh[4]; } ra, rb;
            ra.u4 = *(const uint4*)(OB + swzO(oi * 1024 + cL * 32));
            rb.u4 = *(const uint4*)(OB + swzO(oi * 1024 + cL * 32 + 16));
            float* op = out + ((size_t)((oi * NBATCH + b) * CH + cL)) * HW + p0;
            float4 s0 = { (float)ra.hh[0][0], (float)ra.hh[0][1], (float)ra.hh[1][0], (float)ra.hh[1][1] };
            float4 s1 = { (float)ra.hh[2][0], (float)ra.hh[2][1], (float)ra.hh[3][0], (float)ra.hh[3][1] };
            float4 s2 = { (float)rb.hh[0][0], (float)rb.hh[0][1], (float)rb.hh[1][0], (float)rb.hh[1][1] };
            float4 s3 = { (float)rb.hh[2][0], (float)rb.hh[2][1], (float)rb.hh[3][0], (float)rb.hh[3][1] };
            *(float4*)(op + 0)  = s0;
            *(float4*)(op + 4)  = s1;
            *(float4*)(op + 8)  = s2;
            *(float4*)(op + 12) = s3;
        }
        SYNCR();   // V1 staged; OB readers done before ct1 frag-writes
    }
    // ---- ct = 1 ----
    {
        f32x16 oA = ZERO16, oB = ZERO16;
        {
            int LA = lane * 16;
            f16x8 av0 = *(const f16x8*)(VF + swz(w * 2048 + LA));
            oA = __builtin_amdgcn_mfma_f32_32x32x16_f16(av0, pA0, oA, 0, 0, 0);
            f16x8 av1 = *(const f16x8*)(VF + swz((w + 8) * 2048 + LA));
            oB = __builtin_amdgcn_mfma_f32_32x32x16_f16(av1, pB0, oB, 0, 0, 0);
        }
        {
            int LA = 1024 + lane * 16;
            f16x8 av0 = *(const f16x8*)(VF + swz(w * 2048 + LA));
            oA = __builtin_amdgcn_mfma_f32_32x32x16_f16(av0, pA1, oA, 0, 0, 0);
            f16x8 av1 = *(const f16x8*)(VF + swz((w + 8) * 2048 + LA));
            oB = __builtin_amdgcn_mfma_f32_32x32x16_f16(av1, pB1, oB, 0, 0, 0);
        }
        const int i = lane & 31;
#pragma unroll
        for (int r = 0; r < 16; ++r) {
            int cL = (r & 3) + 8 * (r >> 2) + 4 * h;
            *(f16*)(OB + swzO(i * 1024 + cL * 32 + w * 2))       = (f16)oA[r];
            *(f16*)(OB + swzO(i * 1024 + cL * 32 + (w + 8) * 2)) = (f16)oB[r];
        }
        SYNCR();   // OB complete

#pragma unroll
        for (int rep = 0; rep < 2; ++rep) {
            int row = rep * NT + t;
            int oi = row >> 5, cL = row & 31;
            union { uint4 u4; f16x2 hh[4]; } ra, rb;
            ra.u4 = *(const uint4*)(OB + swzO(oi * 1024 + cL * 32));
            rb.u4 = *(const uint4*)(OB + swzO(oi * 1024 + cL * 32 + 16));
            float* op = out + ((size_t)((oi * NBATCH + b) * CH + 32 + cL)) * HW + p0;
            float4 s0 = { (float)ra.hh[0][0], (float)ra.hh[0][1], (float)ra.hh[1][0], (float)ra.hh[1][1] };
            float4 s1 = { (float)ra.hh[2][0], (float)ra.hh[2][1], (float)ra.hh[3][0], (float)ra.hh[3][1] };
            float4 s2 = { (float)rb.hh[0][0], (float)rb.hh[0][1], (float)rb.hh[1][0], (float)rb.hh[1][1] };
            float4 s3 = { (float)rb.hh[2][0], (float)rb.hh[2][1], (float)rb.hh[3][0], (float)rb.hh[3][1] };
            *(float4*)(op + 0)  = s0;
            *(float4*)(op + 4)  = s1;
            *(float4*)(op + 8)  = s2;
            *(float4*)(op + 12) = s3;
        }
    }
}

extern "C" void kernel_launch(void* const* d_in, const int* in_sizes, int n_in,
                              void* d_out, int out_size, void* d_ws, size_t ws_size,
                              hipStream_t stream) {
    const float* q = (const float*)d_in[0];
    const float* k = (const float*)d_in[1];
    const float* v = (const float*)d_in[2];
    float* o = (float*)d_out;
    dim3 grid(NUNITS);   // 1600 blocks of 512
    box_attn_mfma<<<grid, NT, 0, stream>>>(q, k, v, o);
}